// Round 1
// baseline (115.226 us; speedup 1.0000x reference)
//
#include <hip/hip_runtime.h>
#include <math.h>

#define B_  16
#define NP_ 8192
#define NG_ 128
#define NC_ 80

#define EPS_       1e-7f
#define IOU_THR_   0.5f
#define PEN_       0.1f
#define BOXW_      5.0f
#define SMALLSC_   2.0f
#define SMALLTH_   0.05f

// acc layout per batch (6 floats): [n_match, n_valid, sum_loc, sum_ce, sum_pen, sum_bce]

__global__ __launch_bounds__(256) void yolo_main(
    const float* __restrict__ y_hat,   // (B, NP, 4) xywh
    const float* __restrict__ ygt,     // (B, NG, 4) xywh
    const float* __restrict__ obj,     // (B, NP)
    const float* __restrict__ clsp,    // (B, NP, NC)
    const int*   __restrict__ tgt,     // (B, NG)
    const int*   __restrict__ min_s,   // scalar (int)
    float* __restrict__ acc)           // (B, 6)
{
    __shared__ float gx1[NG_], gy1[NG_], gx2[NG_], gy2[NG_], garea[NG_], gws[NG_];
    __shared__ int   gtc[NG_];
    __shared__ float wred[4][6];

    const int b   = blockIdx.y;
    const int tid = threadIdx.x;
    const int p   = blockIdx.x * 256 + tid;

    // stage GT boxes: xywh -> xyxy, area, small-object weight, target class
    if (tid < NG_) {
        float4 gb = *(const float4*)(ygt + ((size_t)b * NG_ + tid) * 4);
        float x1 = gb.x - gb.z * 0.5f, y1 = gb.y - gb.w * 0.5f;
        float x2 = gb.x + gb.z * 0.5f, y2 = gb.y + gb.w * 0.5f;
        gx1[tid] = x1; gy1[tid] = y1; gx2[tid] = x2; gy2[tid] = y2;
        garea[tid] = (x2 - x1) * (y2 - y1);
        gws[tid]   = ((gb.z < SMALLTH_) || (gb.w < SMALLTH_)) ? SMALLSC_ : 1.0f;
        gtc[tid]   = tgt[b * NG_ + tid];
    }
    __syncthreads();

    const float min_score = (float)min_s[0];

    // pred box -> xyxy
    float4 pb = *(const float4*)(y_hat + ((size_t)b * NP_ + p) * 4);
    float px1 = pb.x - pb.z * 0.5f, py1 = pb.y - pb.w * 0.5f;
    float px2 = pb.x + pb.z * 0.5f, py2 = pb.y + pb.w * 0.5f;
    float area_p = (px2 - px1) * (py2 - py1);

    // argmax IoU over 128 GT boxes, division-free (unions always > 0).
    // strict '>' + ascending j == jnp.argmax first-index semantics.
    float bi_inter = -1.0f, bi_union = 1.0f;
    int   bi = 0;
    #pragma unroll 8
    for (int j = 0; j < NG_; ++j) {
        float ltx = fmaxf(px1, gx1[j]);
        float lty = fmaxf(py1, gy1[j]);
        float rbx = fminf(px2, gx2[j]);
        float rby = fminf(py2, gy2[j]);
        float w = fmaxf(rbx - ltx, 0.0f);
        float h = fmaxf(rby - lty, 0.0f);
        float inter = w * h;
        float uni = area_p + garea[j] - inter;   // reference has no eps here
        bool better = inter * bi_union > bi_inter * uni;
        bi_inter = better ? inter : bi_inter;
        bi_union = better ? uni   : bi_union;
        bi       = better ? j     : bi;
    }
    float max_iou = bi_inter / bi_union;

    float s = obj[(size_t)b * NP_ + p];
    bool valid     = s > min_score;
    bool matched   = valid && (max_iou > IOU_THR_);
    bool unmatched = valid && !matched;

    float f_loc = 0.f, f_ce = 0.f, f_pen = 0.f, f_bce = 0.f;
    float n_m = matched ? 1.f : 0.f;
    float n_v = valid   ? 1.f : 0.f;

    if (unmatched) f_pen = PEN_ * s;

    if (valid) {
        float lbl = matched ? 1.f : 0.f;
        float bce = fmaxf(s, 0.f) - s * lbl + log1pf(expf(-fabsf(s)));
        float w_obj = (matched && s < 0.5f) ? 2.f : 1.f;
        f_bce = bce * w_obj;
    }

    if (matched) {
        float wsm = gws[bi];
        // ---- CIoU(pred, gt[bi]) with eps, matching reference op-for-op ----
        float bx1 = gx1[bi], by1 = gy1[bi], bx2 = gx2[bi], by2 = gy2[bi];
        float b1a = (px2 - px1) * (py2 - py1);
        float b2a = (bx2 - bx1) * (by2 - by1);
        float iw = fmaxf(fminf(px2, bx2) - fmaxf(px1, bx1), 0.f);
        float ih = fmaxf(fminf(py2, by2) - fmaxf(py1, by1), 0.f);
        float inter = iw * ih;
        float uni = b1a + b2a - inter + EPS_;
        float iou = inter / uni;
        float cw = fmaxf(px2, bx2) - fminf(px1, bx1);
        float ch = fmaxf(py2, by2) - fminf(py1, by1);
        float c2 = cw * cw + ch * ch + EPS_;
        float dx = (px1 + px2) * 0.5f - (bx1 + bx2) * 0.5f;
        float dy = (py1 + py2) * 0.5f - (by1 + by2) * 0.5f;
        float rho2 = dx * dx + dy * dy;
        float w1 = px2 - px1, h1 = py2 - py1;
        float w2 = bx2 - bx1, h2 = by2 - by1;
        float dat = atanf(w1 / (h1 + EPS_)) - atanf(w2 / (h2 + EPS_));
        float v = (float)(4.0 / (M_PI * M_PI)) * dat * dat;
        float alpha = v / (1.f - iou + v + EPS_);
        float ciou = iou - (rho2 / c2 + alpha * v);
        f_loc = (1.f - ciou) * wsm;

        // ---- cross-entropy at target class (only matched lanes read logits) ----
        const float* row = clsp + ((size_t)b * NP_ + p) * NC_;
        float m = -INFINITY;
        #pragma unroll
        for (int k = 0; k < NC_ / 4; ++k) {
            float4 v4 = ((const float4*)row)[k];
            m = fmaxf(m, fmaxf(fmaxf(v4.x, v4.y), fmaxf(v4.z, v4.w)));
        }
        float se = 0.f;
        #pragma unroll
        for (int k = 0; k < NC_ / 4; ++k) {
            float4 v4 = ((const float4*)row)[k];
            se += expf(v4.x - m) + expf(v4.y - m) + expf(v4.z - m) + expf(v4.w - m);
        }
        int t = gtc[bi];
        float ce = -(row[t] - m - logf(se));
        f_ce = ce * wsm;
    }

    // ---- block reduction: wave shuffle -> LDS -> one atomicAdd set per block ----
    float vals[6] = { n_m, n_v, f_loc, f_ce, f_pen, f_bce };
    #pragma unroll
    for (int i = 0; i < 6; ++i) {
        float v = vals[i];
        #pragma unroll
        for (int off = 32; off > 0; off >>= 1)
            v += __shfl_down(v, off, 64);
        vals[i] = v;
    }
    int wave = tid >> 6, lane = tid & 63;
    if (lane == 0) {
        #pragma unroll
        for (int i = 0; i < 6; ++i) wred[wave][i] = vals[i];
    }
    __syncthreads();
    if (tid == 0) {
        #pragma unroll
        for (int i = 0; i < 6; ++i) {
            float v = wred[0][i] + wred[1][i] + wred[2][i] + wred[3][i];
            atomicAdd(&acc[b * 6 + i], v);
        }
    }
}

__global__ __launch_bounds__(64) void yolo_final(const float* __restrict__ acc,
                                                 float* __restrict__ out)
{
    int b = threadIdx.x;   // 0..63, batches in 0..15
    float pb = 0.f, cnt = 0.f;
    if (b < B_) {
        float nm   = acc[b * 6 + 0];
        float nv   = acc[b * 6 + 1];
        float sloc = acc[b * 6 + 2];
        float sce  = acc[b * 6 + 3];
        float spen = acc[b * 6 + 4];
        float sbce = acc[b * 6 + 5];
        float loc = nm > 0.f ? sloc / nm : 0.f;
        float ce  = nm > 0.f ? sce  / nm : 0.f;
        float ob  = nv > 0.f ? sbce / nv : 0.f;
        float per = BOXW_ * loc + ob + spen + ce;
        if (nv > 0.f) { pb = per; cnt = 1.f; }
    }
    #pragma unroll
    for (int off = 32; off > 0; off >>= 1) {
        pb  += __shfl_down(pb,  off, 64);
        cnt += __shfl_down(cnt, off, 64);
    }
    if (b == 0) out[0] = pb / fmaxf(cnt, 1.f);
}

extern "C" void kernel_launch(void* const* d_in, const int* in_sizes, int n_in,
                              void* d_out, int out_size, void* d_ws, size_t ws_size,
                              hipStream_t stream) {
    const float* y_hat = (const float*)d_in[0];
    const float* ygt   = (const float*)d_in[1];
    const float* obj   = (const float*)d_in[2];
    const float* clsp  = (const float*)d_in[3];
    const int*   tgt   = (const int*)d_in[4];
    const int*   mins  = (const int*)d_in[5];
    float* acc = (float*)d_ws;      // 16 batches x 6 accumulators
    float* out = (float*)d_out;

    hipMemsetAsync(acc, 0, B_ * 6 * sizeof(float), stream);

    dim3 grid(NP_ / 256, B_);
    yolo_main<<<grid, 256, 0, stream>>>(y_hat, ygt, obj, clsp, tgt, mins, acc);
    yolo_final<<<1, 64, 0, stream>>>(acc, out);
}

// Round 2
// 105.972 us; speedup vs baseline: 1.0873x; 1.0873x over previous
//
#include <hip/hip_runtime.h>
#include <math.h>

#define B_  16
#define NP_ 8192
#define NG_ 128
#define NC_ 80
#define PPB_ 128               // predictions per block (block = 256 thr, 2 halves)
#define NBX_ (NP_ / PPB_)      // 64 blocks along preds per batch

#define EPS_       1e-7f
#define IOU_THR_   0.5f
#define PEN_       0.1f
#define BOXW_      5.0f
#define SMALLSC_   2.0f
#define SMALLTH_   0.05f

// d_ws partials layout: part[(b*NBX_ + bx)*6 + i], every block writes its own
// slot unconditionally -> no zero-init, no atomics.
// per-batch components i: [n_match, n_valid, sum_loc, sum_ce, sum_pen, sum_bce]

__global__ __launch_bounds__(256) void yolo_main(
    const float* __restrict__ y_hat,   // (B, NP, 4) xywh
    const float* __restrict__ ygt,     // (B, NG, 4) xywh
    const float* __restrict__ obj,     // (B, NP)
    const float* __restrict__ clsp,    // (B, NP, NC)
    const int*   __restrict__ tgt,     // (B, NG)
    const int*   __restrict__ min_s,   // scalar (int)
    float* __restrict__ part)          // (B*NBX_, 6)
{
    __shared__ float4 g4[NG_];                 // gt xyxy
    __shared__ float  garea[NG_], gws[NG_];
    __shared__ int    gtc[NG_];
    __shared__ float  mbuf[PPB_][4];           // half1 argmax state {inter, uni, bi, pad}
    __shared__ float  wred[4][6];

    const int b    = blockIdx.y;
    const int tid  = threadIdx.x;
    const int pl   = tid & (PPB_ - 1);         // local pred id
    const int half = tid >> 7;                 // 0: j in [0,64), 1: j in [64,128)
    const int p    = blockIdx.x * PPB_ + pl;

    // stage GT boxes: xywh -> xyxy(float4), area, small-obj weight, class
    if (tid < NG_) {
        float4 gb = *(const float4*)(ygt + ((size_t)b * NG_ + tid) * 4);
        float x1 = gb.x - gb.z * 0.5f, y1 = gb.y - gb.w * 0.5f;
        float x2 = gb.x + gb.z * 0.5f, y2 = gb.y + gb.w * 0.5f;
        g4[tid] = make_float4(x1, y1, x2, y2);
        garea[tid] = (x2 - x1) * (y2 - y1);
        gws[tid]   = ((gb.z < SMALLTH_) || (gb.w < SMALLTH_)) ? SMALLSC_ : 1.0f;
        gtc[tid]   = tgt[b * NG_ + tid];
    }
    __syncthreads();

    const float min_score = (float)min_s[0];

    // pred box -> xyxy (both halves load the same pred's box; coalesced)
    float4 pb = *(const float4*)(y_hat + ((size_t)b * NP_ + p) * 4);
    float px1 = pb.x - pb.z * 0.5f, py1 = pb.y - pb.w * 0.5f;
    float px2 = pb.x + pb.z * 0.5f, py2 = pb.y + pb.w * 0.5f;
    float area_p = (px2 - px1) * (py2 - py1);

    // half-range argmax IoU, division-free (unions > 0).
    // strict '>' + ascending j == first-index (jnp.argmax) semantics.
    float bi_inter = -1.0f, bi_union = 1.0f;
    int   bi = half * 64;
    const int j0 = half * 64;
    #pragma unroll 8
    for (int jj = 0; jj < 64; ++jj) {
        int j = j0 + jj;
        float4 g = g4[j];
        float w = fmaxf(fminf(px2, g.z) - fmaxf(px1, g.x), 0.0f);
        float h = fmaxf(fminf(py2, g.w) - fmaxf(py1, g.y), 0.0f);
        float inter = w * h;
        float uni = area_p + garea[j] - inter;   // reference iou_mat has no eps
        bool better = inter * bi_union > bi_inter * uni;
        bi_inter = better ? inter : bi_inter;
        bi_union = better ? uni   : bi_union;
        bi       = better ? j     : bi;
    }

    // merge halves: half1 publishes, half0 merges (tie -> half0, lower j: correct)
    if (half == 1) {
        mbuf[pl][0] = bi_inter;
        mbuf[pl][1] = bi_union;
        mbuf[pl][2] = (float)bi;
    }
    __syncthreads();

    float f_loc = 0.f, f_ce = 0.f, f_pen = 0.f, f_bce = 0.f, n_m = 0.f, n_v = 0.f;

    if (half == 0) {
        float oi = mbuf[pl][0], ou = mbuf[pl][1];
        if (oi * bi_union > bi_inter * ou) {
            bi_inter = oi; bi_union = ou; bi = (int)mbuf[pl][2];
        }
        float max_iou = bi_inter / bi_union;

        float s = obj[(size_t)b * NP_ + p];
        bool valid     = s > min_score;
        bool matched   = valid && (max_iou > IOU_THR_);
        bool unmatched = valid && !matched;

        n_m = matched ? 1.f : 0.f;
        n_v = valid   ? 1.f : 0.f;
        if (unmatched) f_pen = PEN_ * s;

        if (valid) {
            float lbl = matched ? 1.f : 0.f;
            float bce = fmaxf(s, 0.f) - s * lbl + log1pf(expf(-fabsf(s)));
            float w_obj = (matched && s < 0.5f) ? 2.f : 1.f;
            f_bce = bce * w_obj;
        }

        if (matched) {
            float wsm = gws[bi];
            float4 g = g4[bi];
            float bx1 = g.x, by1 = g.y, bx2 = g.z, by2 = g.w;
            // CIoU(pred, gt[bi]) op-for-op with reference (with eps)
            float b1a = (px2 - px1) * (py2 - py1);
            float b2a = (bx2 - bx1) * (by2 - by1);
            float iw = fmaxf(fminf(px2, bx2) - fmaxf(px1, bx1), 0.f);
            float ih = fmaxf(fminf(py2, by2) - fmaxf(py1, by1), 0.f);
            float inter = iw * ih;
            float uni = b1a + b2a - inter + EPS_;
            float iou = inter / uni;
            float cw = fmaxf(px2, bx2) - fminf(px1, bx1);
            float ch = fmaxf(py2, by2) - fminf(py1, by1);
            float c2 = cw * cw + ch * ch + EPS_;
            float dx = (px1 + px2) * 0.5f - (bx1 + bx2) * 0.5f;
            float dy = (py1 + py2) * 0.5f - (by1 + by2) * 0.5f;
            float rho2 = dx * dx + dy * dy;
            float w1 = px2 - px1, h1 = py2 - py1;
            float w2 = bx2 - bx1, h2 = by2 - by1;
            float dat = atanf(w1 / (h1 + EPS_)) - atanf(w2 / (h2 + EPS_));
            float v = (float)(4.0 / (M_PI * M_PI)) * dat * dat;
            float alpha = v / (1.f - iou + v + EPS_);
            float ciou = iou - (rho2 / c2 + alpha * v);
            f_loc = (1.f - ciou) * wsm;

            // cross-entropy at target class (only matched lanes touch logits)
            const float* row = clsp + ((size_t)b * NP_ + p) * NC_;
            float m = -INFINITY;
            #pragma unroll
            for (int k = 0; k < NC_ / 4; ++k) {
                float4 v4 = ((const float4*)row)[k];
                m = fmaxf(m, fmaxf(fmaxf(v4.x, v4.y), fmaxf(v4.z, v4.w)));
            }
            float se = 0.f;
            #pragma unroll
            for (int k = 0; k < NC_ / 4; ++k) {
                float4 v4 = ((const float4*)row)[k];
                se += expf(v4.x - m) + expf(v4.y - m) + expf(v4.z - m) + expf(v4.w - m);
            }
            int t = gtc[bi];
            float ce = -(row[t] - m - logf(se));
            f_ce = ce * wsm;
        }
    }

    // block reduction (half1 lanes contribute zeros): wave shuffle -> LDS -> slot
    float vals[6] = { n_m, n_v, f_loc, f_ce, f_pen, f_bce };
    #pragma unroll
    for (int i = 0; i < 6; ++i) {
        float v = vals[i];
        #pragma unroll
        for (int off = 32; off > 0; off >>= 1)
            v += __shfl_down(v, off, 64);
        vals[i] = v;
    }
    int wave = tid >> 6, lane = tid & 63;
    if (lane == 0) {
        #pragma unroll
        for (int i = 0; i < 6; ++i) wred[wave][i] = vals[i];
    }
    __syncthreads();
    if (tid == 0) {
        float* slot = part + ((size_t)b * NBX_ + blockIdx.x) * 6;
        #pragma unroll
        for (int i = 0; i < 6; ++i)
            slot[i] = wred[0][i] + wred[1][i] + wred[2][i] + wred[3][i];
    }
}

// one wave: 4 lanes per batch, each lane sums 16 of the 64 block-slots
__global__ __launch_bounds__(64) void yolo_final(const float* __restrict__ part,
                                                 float* __restrict__ out)
{
    int lane = threadIdx.x;        // 0..63
    int b    = lane >> 2;          // batch 0..15
    int sub  = lane & 3;

    float v[6] = {0.f, 0.f, 0.f, 0.f, 0.f, 0.f};
    for (int k = 0; k < NBX_ / 4; ++k) {
        const float* slot = part + ((size_t)b * NBX_ + sub + 4 * k) * 6;
        #pragma unroll
        for (int i = 0; i < 6; ++i) v[i] += slot[i];
    }
    // sum over the 4 lanes of this batch
    #pragma unroll
    for (int i = 0; i < 6; ++i) {
        v[i] += __shfl_xor(v[i], 1, 64);
        v[i] += __shfl_xor(v[i], 2, 64);
    }

    float pbv = 0.f, cnt = 0.f;
    if (sub == 0) {
        float nm = v[0], nv = v[1];
        float loc = nm > 0.f ? v[2] / nm : 0.f;
        float ce  = nm > 0.f ? v[3] / nm : 0.f;
        float ob  = nv > 0.f ? v[5] / nv : 0.f;
        float per = BOXW_ * loc + ob + v[4] + ce;
        if (nv > 0.f) { pbv = per; cnt = 1.f; }
    }
    #pragma unroll
    for (int off = 32; off > 0; off >>= 1) {
        pbv += __shfl_down(pbv, off, 64);
        cnt += __shfl_down(cnt, off, 64);
    }
    if (lane == 0) out[0] = pbv / fmaxf(cnt, 1.f);
}

extern "C" void kernel_launch(void* const* d_in, const int* in_sizes, int n_in,
                              void* d_out, int out_size, void* d_ws, size_t ws_size,
                              hipStream_t stream) {
    const float* y_hat = (const float*)d_in[0];
    const float* ygt   = (const float*)d_in[1];
    const float* obj   = (const float*)d_in[2];
    const float* clsp  = (const float*)d_in[3];
    const int*   tgt   = (const int*)d_in[4];
    const int*   mins  = (const int*)d_in[5];
    float* part = (float*)d_ws;     // (16*64) x 6 partials, fully overwritten
    float* out  = (float*)d_out;

    dim3 grid(NBX_, B_);
    yolo_main<<<grid, 256, 0, stream>>>(y_hat, ygt, obj, clsp, tgt, mins, part);
    yolo_final<<<1, 64, 0, stream>>>(part, out);
}

// Round 3
// 105.611 us; speedup vs baseline: 1.0910x; 1.0034x over previous
//
#include <hip/hip_runtime.h>
#include <math.h>

#define B_  16
#define NP_ 8192
#define NG_ 128
#define NC_ 80
#define PPB_ 64                // predictions per block (block = 256 thr, 4 quarters)
#define NBX_ (NP_ / PPB_)      // 128 blocks along preds per batch

#define EPS_       1e-7f
#define IOU_THR_   0.5f
#define PEN_       0.1f
#define BOXW_      5.0f
#define SMALLSC_   2.0f
#define SMALLTH_   0.05f

// d_ws partials layout: part[(b*NBX_ + bx)*6 + i], every block writes its own
// slot unconditionally -> no zero-init, no atomics.
// components i: [n_match, n_valid, sum_loc, sum_ce, sum_pen, sum_bce]

__global__ __launch_bounds__(256) void yolo_main(
    const float* __restrict__ y_hat,   // (B, NP, 4) xywh
    const float* __restrict__ ygt,     // (B, NG, 4) xywh
    const float* __restrict__ obj,     // (B, NP)
    const float* __restrict__ clsp,    // (B, NP, NC)
    const int*   __restrict__ tgt,     // (B, NG)
    const int*   __restrict__ min_s,   // scalar (int)
    float* __restrict__ part)          // (B*NBX_, 6)
{
    __shared__ float4 g4[NG_];                 // gt xyxy
    __shared__ float  garea[NG_], gws[NG_];
    __shared__ int    gtc[NG_];
    __shared__ float4 mbuf[3][PPB_];           // quarters 1..3 publish {inter, uni, bi, 0}

    const int b   = blockIdx.y;
    const int tid = threadIdx.x;
    const int pl  = tid & 63;                  // local pred id (lane)
    const int q   = tid >> 6;                  // quarter: j in [32q, 32q+32)
    const int p   = blockIdx.x * PPB_ + pl;

    // stage GT boxes: xywh -> xyxy(float4), area, small-obj weight, class
    if (tid < NG_) {
        float4 gb = *(const float4*)(ygt + ((size_t)b * NG_ + tid) * 4);
        float x1 = gb.x - gb.z * 0.5f, y1 = gb.y - gb.w * 0.5f;
        float x2 = gb.x + gb.z * 0.5f, y2 = gb.y + gb.w * 0.5f;
        g4[tid] = make_float4(x1, y1, x2, y2);
        garea[tid] = (x2 - x1) * (y2 - y1);
        gws[tid]   = ((gb.z < SMALLTH_) || (gb.w < SMALLTH_)) ? SMALLSC_ : 1.0f;
        gtc[tid]   = tgt[b * NG_ + tid];
    }
    __syncthreads();

    const float min_score = (float)min_s[0];

    // pred box -> xyxy (all 4 quarters of a pred load the same box; L1-served)
    float4 pb = *(const float4*)(y_hat + ((size_t)b * NP_ + p) * 4);
    float px1 = pb.x - pb.z * 0.5f, py1 = pb.y - pb.w * 0.5f;
    float px2 = pb.x + pb.z * 0.5f, py2 = pb.y + pb.w * 0.5f;
    float area_p = (px2 - px1) * (py2 - py1);

    // quarter-range argmax IoU, division-free (unions > 0).
    // strict '>' + ascending j == first-index (jnp.argmax) semantics.
    float bi_inter = -1.0f, bi_union = 1.0f;
    const int j0 = q * 32;
    int bi = j0;
    #pragma unroll 8
    for (int jj = 0; jj < 32; ++jj) {
        int j = j0 + jj;
        float4 g = g4[j];                       // wave-uniform addr -> LDS broadcast
        float w = fmaxf(fminf(px2, g.z) - fmaxf(px1, g.x), 0.0f);
        float h = fmaxf(fminf(py2, g.w) - fmaxf(py1, g.y), 0.0f);
        float inter = w * h;
        float uni = area_p + garea[j] - inter;  // reference iou_mat has no eps
        bool better = inter * bi_union > bi_inter * uni;
        bi_inter = better ? inter : bi_inter;
        bi_union = better ? uni   : bi_union;
        bi       = better ? j     : bi;
    }

    // quarters 1..3 publish; quarter 0 (wave 0) merges in ascending order
    if (q != 0) mbuf[q - 1][pl] = make_float4(bi_inter, bi_union, (float)bi, 0.f);
    __syncthreads();
    if (q != 0) return;   // all waves already passed the barrier

    #pragma unroll
    for (int k = 0; k < 3; ++k) {
        float4 o = mbuf[k][pl];
        if (o.x * bi_union > bi_inter * o.y) {  // strict > keeps lowest j on ties
            bi_inter = o.x; bi_union = o.y; bi = (int)o.z;
        }
    }
    float max_iou = bi_inter / bi_union;

    float s = obj[(size_t)b * NP_ + p];
    bool valid     = s > min_score;
    bool matched   = valid && (max_iou > IOU_THR_);
    bool unmatched = valid && !matched;

    float f_loc = 0.f, f_ce = 0.f, f_pen = 0.f, f_bce = 0.f;
    float n_m = matched ? 1.f : 0.f;
    float n_v = valid   ? 1.f : 0.f;
    if (unmatched) f_pen = PEN_ * s;

    if (valid) {
        float lbl = matched ? 1.f : 0.f;
        float bce = fmaxf(s, 0.f) - s * lbl + log1pf(expf(-fabsf(s)));
        float w_obj = (matched && s < 0.5f) ? 2.f : 1.f;
        f_bce = bce * w_obj;
    }

    if (matched) {
        float wsm = gws[bi];
        float4 g = g4[bi];
        float bx1 = g.x, by1 = g.y, bx2 = g.z, by2 = g.w;
        // CIoU(pred, gt[bi]) op-for-op with reference (with eps)
        float b1a = (px2 - px1) * (py2 - py1);
        float b2a = (bx2 - bx1) * (by2 - by1);
        float iw = fmaxf(fminf(px2, bx2) - fmaxf(px1, bx1), 0.f);
        float ih = fmaxf(fminf(py2, by2) - fmaxf(py1, by1), 0.f);
        float inter = iw * ih;
        float uni = b1a + b2a - inter + EPS_;
        float iou = inter / uni;
        float cw = fmaxf(px2, bx2) - fminf(px1, bx1);
        float ch = fmaxf(py2, by2) - fminf(py1, by1);
        float c2 = cw * cw + ch * ch + EPS_;
        float dx = (px1 + px2) * 0.5f - (bx1 + bx2) * 0.5f;
        float dy = (py1 + py2) * 0.5f - (by1 + by2) * 0.5f;
        float rho2 = dx * dx + dy * dy;
        float w1 = px2 - px1, h1 = py2 - py1;
        float w2 = bx2 - bx1, h2 = by2 - by1;
        float dat = atanf(w1 / (h1 + EPS_)) - atanf(w2 / (h2 + EPS_));
        float v = (float)(4.0 / (M_PI * M_PI)) * dat * dat;
        float alpha = v / (1.f - iou + v + EPS_);
        float ciou = iou - (rho2 / c2 + alpha * v);
        f_loc = (1.f - ciou) * wsm;

        // cross-entropy at target class (only matched lanes touch logits)
        const float* row = clsp + ((size_t)b * NP_ + p) * NC_;
        float m = -INFINITY;
        #pragma unroll
        for (int k = 0; k < NC_ / 4; ++k) {
            float4 v4 = ((const float4*)row)[k];
            m = fmaxf(m, fmaxf(fmaxf(v4.x, v4.y), fmaxf(v4.z, v4.w)));
        }
        float se = 0.f;
        #pragma unroll
        for (int k = 0; k < NC_ / 4; ++k) {
            float4 v4 = ((const float4*)row)[k];
            se += expf(v4.x - m) + expf(v4.y - m) + expf(v4.z - m) + expf(v4.w - m);
        }
        int t = gtc[bi];
        float ce = -(row[t] - m - logf(se));
        f_ce = ce * wsm;
    }

    // wave 0 owns everything: shuffle-reduce and write the block's slot directly
    float vals[6] = { n_m, n_v, f_loc, f_ce, f_pen, f_bce };
    #pragma unroll
    for (int i = 0; i < 6; ++i) {
        float v = vals[i];
        #pragma unroll
        for (int off = 32; off > 0; off >>= 1)
            v += __shfl_down(v, off, 64);
        vals[i] = v;
    }
    if (pl == 0) {
        float* slot = part + ((size_t)b * NBX_ + blockIdx.x) * 6;
        #pragma unroll
        for (int i = 0; i < 6; ++i) slot[i] = vals[i];
    }
}

// one wave: 4 lanes per batch, each lane sums 32 of the 128 block-slots
__global__ __launch_bounds__(64) void yolo_final(const float* __restrict__ part,
                                                 float* __restrict__ out)
{
    int lane = threadIdx.x;        // 0..63
    int b    = lane >> 2;          // batch 0..15
    int sub  = lane & 3;

    float v[6] = {0.f, 0.f, 0.f, 0.f, 0.f, 0.f};
    for (int k = 0; k < NBX_ / 4; ++k) {
        const float* slot = part + ((size_t)b * NBX_ + sub + 4 * k) * 6;
        #pragma unroll
        for (int i = 0; i < 6; ++i) v[i] += slot[i];
    }
    #pragma unroll
    for (int i = 0; i < 6; ++i) {
        v[i] += __shfl_xor(v[i], 1, 64);
        v[i] += __shfl_xor(v[i], 2, 64);
    }

    float pbv = 0.f, cnt = 0.f;
    if (sub == 0) {
        float nm = v[0], nv = v[1];
        float loc = nm > 0.f ? v[2] / nm : 0.f;
        float ce  = nm > 0.f ? v[3] / nm : 0.f;
        float ob  = nv > 0.f ? v[5] / nv : 0.f;
        float per = BOXW_ * loc + ob + v[4] + ce;
        if (nv > 0.f) { pbv = per; cnt = 1.f; }
    }
    #pragma unroll
    for (int off = 32; off > 0; off >>= 1) {
        pbv += __shfl_down(pbv, off, 64);
        cnt += __shfl_down(cnt, off, 64);
    }
    if (lane == 0) out[0] = pbv / fmaxf(cnt, 1.f);
}

extern "C" void kernel_launch(void* const* d_in, const int* in_sizes, int n_in,
                              void* d_out, int out_size, void* d_ws, size_t ws_size,
                              hipStream_t stream) {
    const float* y_hat = (const float*)d_in[0];
    const float* ygt   = (const float*)d_in[1];
    const float* obj   = (const float*)d_in[2];
    const float* clsp  = (const float*)d_in[3];
    const int*   tgt   = (const int*)d_in[4];
    const int*   mins  = (const int*)d_in[5];
    float* part = (float*)d_ws;     // (16*128) x 6 partials, fully overwritten
    float* out  = (float*)d_out;

    dim3 grid(NBX_, B_);
    yolo_main<<<grid, 256, 0, stream>>>(y_hat, ygt, obj, clsp, tgt, mins, part);
    yolo_final<<<1, 64, 0, stream>>>(part, out);
}